// Round 2
// baseline (322.878 us; speedup 1.0000x reference)
//
#include <hip/hip_runtime.h>
#include <stdint.h>

// ---------------------------------------------------------------------------
// Problem: B=32, C=4, S=256, L=256, Din=Dout=256
//   corr[b,s,t] = dot(fm[b,s,:], fm[b,t,:])
//   MLP 1->16->8->2 (exact GELU), hard gumbel-softmax (jax key 42, threefry)
//   adj binary, diag forced 1, row-normalized; X = adj @ F ; out = X @ Wl + bl
// Decision path computed in f64; threefry bits replicated exactly using the
// PARTITIONABLE scheme (jax_threefry_partitionable=True, default since
// jax 0.4.36): bits[i] = out0 ^ out1 of threefry2x32(key, (0, i)).
// ---------------------------------------------------------------------------

__device__ __forceinline__ void threefry2x32(uint32_t x0, uint32_t x1,
                                             uint32_t& o0, uint32_t& o1) {
  // key = (0, 42) from jax.random.key(42)
  const uint32_t ks0 = 0u;
  const uint32_t ks1 = 42u;
  const uint32_t ks2 = 0x1BD11BDAu ^ ks0 ^ ks1;
  const uint32_t ks[3] = {ks0, ks1, ks2};
  const uint32_t rot[2][4] = {{13u, 15u, 26u, 6u}, {17u, 29u, 16u, 24u}};
  x0 += ks0;
  x1 += ks1;
#pragma unroll
  for (int i = 0; i < 5; ++i) {
#pragma unroll
    for (int j = 0; j < 4; ++j) {
      const uint32_t r = rot[i & 1][j];
      x0 += x1;
      x1 = (x1 << r) | (x1 >> (32u - r));
      x1 ^= x0;
    }
    x0 += ks[(i + 1) % 3];
    x1 += ks[(i + 2) % 3] + (uint32_t)(i + 1);
  }
  o0 = x0;
  o1 = x1;
}

// Gumbel noise at flat index j of shape (32, 65536, 2).
// Partitionable threefry: ctr = (hi=0, lo=j); bits = o0 ^ o1.
__device__ __forceinline__ double gumbel_at(uint32_t j) {
  uint32_t o0, o1;
  threefry2x32(0u, j, o0, o1);
  const uint32_t bits = o0 ^ o1;
  // jax uniform: frac in [0,1) from top 23 bits, u = max(1e-10, frac + 1e-10)
  uint32_t fb = (bits >> 9) | 0x3F800000u;
  float frac = __uint_as_float(fb) - 1.0f;
  float u = frac + 1e-10f;           // frac*(maxval-minval==1.0f) + minval
  u = fmaxf(u, 1e-10f);
  double t = -log((double)u);        // > 0
  return -log(t);
}

__device__ __forceinline__ double gelu_d(double x) {
  return 0.5 * x * (1.0 + erf(x * 0.70710678118654752440));
}

// ---------------------------------------------------------------------------
// Kernel 1: corr + MLP + gumbel -> binary adj (diag forced to 1)
// grid (16,16,32): x = t-tile, y = s-tile, z = b.  256 threads = 16x16 tile.
// ---------------------------------------------------------------------------
__global__ __launch_bounds__(256) void corr_adj_kernel(
    const float* __restrict__ fm,
    const float* __restrict__ W1, const float* __restrict__ b1,
    const float* __restrict__ W2, const float* __restrict__ b2,
    const float* __restrict__ W3, const float* __restrict__ b3,
    float* __restrict__ adj) {
  const int b = blockIdx.z;
  const int s0 = blockIdx.y * 16;
  const int t0 = blockIdx.x * 16;

  __shared__ float smS[16][260];  // pad 260: float4-aligned rows, 2-way max
  __shared__ float smT[16][260];

  const int tid = threadIdx.x;
  {
    const float* baseS = fm + ((size_t)b * 256 + s0) * 256;
    const float* baseT = fm + ((size_t)b * 256 + t0) * 256;
#pragma unroll
    for (int i = 0; i < 4; ++i) {
      int idx = tid + i * 256;     // 0..1023
      int r = idx >> 6;            // row 0..15
      int c = (idx & 63) * 4;      // col 0..252
      *(float4*)(&smS[r][c]) = *(const float4*)(baseS + r * 256 + c);
      *(float4*)(&smT[r][c]) = *(const float4*)(baseT + r * 256 + c);
    }
  }
  __syncthreads();

  const int sl = tid >> 4;
  const int tl = tid & 15;

  double acc = 0.0;
#pragma unroll 8
  for (int k = 0; k < 256; k += 4) {
    float4 a = *(const float4*)(&smS[sl][k]);
    float4 v = *(const float4*)(&smT[tl][k]);
    acc += (double)a.x * (double)v.x;
    acc += (double)a.y * (double)v.y;
    acc += (double)a.z * (double)v.z;
    acc += (double)a.w * (double)v.w;
  }

  // tiny MLP in f64
  double h1[16];
#pragma unroll
  for (int i = 0; i < 16; ++i)
    h1[i] = gelu_d(acc * (double)W1[i] + (double)b1[i]);

  double h2[8];
#pragma unroll
  for (int j = 0; j < 8; ++j) {
    double v = (double)b2[j];
#pragma unroll
    for (int i = 0; i < 16; ++i) v += h1[i] * (double)W2[i * 8 + j];
    h2[j] = gelu_d(v);
  }

  double l0 = (double)b3[0], l1 = (double)b3[1];
#pragma unroll
  for (int j = 0; j < 8; ++j) {
    l0 += h2[j] * (double)W3[j * 2 + 0];
    l1 += h2[j] * (double)W3[j * 2 + 1];
  }

  const int s = s0 + sl;
  const int t = t0 + tl;
  const uint32_t base = ((uint32_t)b << 16) | ((uint32_t)s << 8) | (uint32_t)t;
  const double g0 = gumbel_at(2u * base);
  const double g1 = gumbel_at(2u * base + 1u);

  // argmax picks index 0 on ties -> adj = y[...,0]
  float a = (l0 + g0 >= l1 + g1) ? 1.0f : 0.0f;
  if (t == s) a = 1.0f;  // adj + (1-adj)*I
  adj[((size_t)b << 16) | ((uint32_t)s << 8) | (uint32_t)t] = a;
}

// ---------------------------------------------------------------------------
// Kernel 2: row-normalize adj in place. grid 8192 (= B*S rows), 64 threads.
// r = 1.0f/rowsum (rowsum is an exact small integer); entries r or 0 exactly.
// ---------------------------------------------------------------------------
__global__ __launch_bounds__(64) void rownorm_kernel(float* __restrict__ adj) {
  const size_t row = blockIdx.x;
  float* p = adj + row * 256;
  const int lane = threadIdx.x;
  float4 v = ((const float4*)p)[lane];
  float sum = v.x + v.y + v.z + v.w;
#pragma unroll
  for (int off = 32; off; off >>= 1) sum += __shfl_xor(sum, off);
  const float r = 1.0f / sum;
  v.x *= r; v.y *= r; v.z *= r; v.w *= r;
  ((float4*)p)[lane] = v;
}

// ---------------------------------------------------------------------------
// Kernels 3/4: f32 GEMM, M=N=K=256 per batch z.
// BM=BN=128, BK=8, 256 threads, 8x8 microtile as 2x2 blocks of 4x4.
// A batch = z / aDiv; B batch = z (or shared if bShared).
// ---------------------------------------------------------------------------
__global__ __launch_bounds__(256) void gemm_kernel(
    const float* __restrict__ A, const float* __restrict__ B,
    const float* __restrict__ bias, float* __restrict__ C,
    int aDiv, int bShared) {
  const int z = blockIdx.z;
  const float* Ab = A + (size_t)(z / aDiv) * 65536;
  const float* Bb = bShared ? B : (B + (size_t)z * 65536);
  float* Cb = C + (size_t)z * 65536;

  const int row0 = blockIdx.y * 128;
  const int col0 = blockIdx.x * 128;

  __shared__ float As[8][132];  // transposed A tile: As[k][m]
  __shared__ float Bs[8][132];

  const int tid = threadIdx.x;
  const int tx = tid & 15;
  const int ty = tid >> 4;

  float acc[2][2][4][4];
#pragma unroll
  for (int a = 0; a < 2; ++a)
#pragma unroll
    for (int bq = 0; bq < 2; ++bq)
#pragma unroll
      for (int i = 0; i < 4; ++i)
#pragma unroll
        for (int j = 0; j < 4; ++j) acc[a][bq][i][j] = 0.0f;

  for (int k0 = 0; k0 < 256; k0 += 8) {
    {  // A tile 128x8 -> As[k][m]
      int r = tid >> 1, c = (tid & 1) * 4;
      float4 v = *(const float4*)(Ab + (size_t)(row0 + r) * 256 + k0 + c);
      As[c + 0][r] = v.x;
      As[c + 1][r] = v.y;
      As[c + 2][r] = v.z;
      As[c + 3][r] = v.w;
    }
    {  // B tile 8x128
      int r = tid >> 5, c = (tid & 31) * 4;
      *(float4*)(&Bs[r][c]) =
          *(const float4*)(Bb + (size_t)(k0 + r) * 256 + col0 + c);
    }
    __syncthreads();

#pragma unroll
    for (int kk = 0; kk < 8; ++kk) {
      float a0[4], a1[4], b0[4], b1[4];
      *(float4*)a0 = *(const float4*)(&As[kk][ty * 4]);
      *(float4*)a1 = *(const float4*)(&As[kk][ty * 4 + 64]);
      *(float4*)b0 = *(const float4*)(&Bs[kk][tx * 4]);
      *(float4*)b1 = *(const float4*)(&Bs[kk][tx * 4 + 64]);
#pragma unroll
      for (int i = 0; i < 4; ++i)
#pragma unroll
        for (int j = 0; j < 4; ++j) {
          acc[0][0][i][j] += a0[i] * b0[j];
          acc[0][1][i][j] += a0[i] * b1[j];
          acc[1][0][i][j] += a1[i] * b0[j];
          acc[1][1][i][j] += a1[i] * b1[j];
        }
    }
    __syncthreads();
  }

#pragma unroll
  for (int ih = 0; ih < 2; ++ih)
#pragma unroll
    for (int i = 0; i < 4; ++i) {
      const int row = row0 + ih * 64 + ty * 4 + i;
#pragma unroll
      for (int jh = 0; jh < 2; ++jh) {
        const int col = col0 + jh * 64 + tx * 4;
        float4 o;
        o.x = acc[ih][jh][i][0];
        o.y = acc[ih][jh][i][1];
        o.z = acc[ih][jh][i][2];
        o.w = acc[ih][jh][i][3];
        if (bias) {
          float4 bv = *(const float4*)(bias + col);
          o.x += bv.x; o.y += bv.y; o.z += bv.z; o.w += bv.w;
        }
        *(float4*)(Cb + (size_t)row * 256 + col) = o;
      }
    }
}

extern "C" void kernel_launch(void* const* d_in, const int* in_sizes, int n_in,
                              void* d_out, int out_size, void* d_ws,
                              size_t ws_size, hipStream_t stream) {
  const float* features = (const float*)d_in[0];
  const float* fm       = (const float*)d_in[1];
  const float* W1 = (const float*)d_in[2];
  const float* b1 = (const float*)d_in[3];
  const float* W2 = (const float*)d_in[4];
  const float* b2 = (const float*)d_in[5];
  const float* W3 = (const float*)d_in[6];
  const float* b3 = (const float*)d_in[7];
  const float* Wl = (const float*)d_in[8];
  const float* bl = (const float*)d_in[9];
  float* out = (float*)d_out;

  // workspace: adj (32*256*256 f32 = 8.4MB) + X (32*4*256*256 f32 = 33.5MB)
  float* adj = (float*)d_ws;
  float* X = (float*)d_ws + (size_t)32 * 256 * 256;

  corr_adj_kernel<<<dim3(16, 16, 32), 256, 0, stream>>>(fm, W1, b1, W2, b2, W3,
                                                        b3, adj);
  rownorm_kernel<<<dim3(8192), 64, 0, stream>>>(adj);
  // X[b,c] = adj[b] @ F[b,c]
  gemm_kernel<<<dim3(2, 2, 128), 256, 0, stream>>>(adj, features, nullptr, X,
                                                   4, 0);
  // out[b,c] = X[b,c] @ Wl + bl
  gemm_kernel<<<dim3(2, 2, 128), 256, 0, stream>>>(X, Wl, bl, out, 1, 1);
}

// Round 3
// 232.339 us; speedup vs baseline: 1.3897x; 1.3897x over previous
//
#include <hip/hip_runtime.h>
#include <stdint.h>

// ---------------------------------------------------------------------------
// B=32, C=4, S=256, L=256, Din=Dout=256
//   corr[b,s,t] = dot(fm[b,s,:], fm[b,t,:])
//   MLP 1->16->8->2 (exact GELU), hard gumbel-softmax (jax key 42, threefry,
//   partitionable scheme), adj binary, diag=1, row-normalized;
//   X = adj @ F ; out = X @ Wl + bl
// Decision path: f32 fast path with |margin| >= 1e-3 guard; exact f64
// recompute (bit-identical to the round-2 all-f64 path) otherwise.
// Symmetry: corr and the MLP are shared between (s,t) and (t,s); only the
// gumbel draws differ -> triangular grid, 2 decisions per thread.
// ---------------------------------------------------------------------------

__device__ __forceinline__ void threefry2x32(uint32_t x0, uint32_t x1,
                                             uint32_t& o0, uint32_t& o1) {
  // key = (0, 42) from jax.random.key(42)
  const uint32_t ks0 = 0u;
  const uint32_t ks1 = 42u;
  const uint32_t ks2 = 0x1BD11BDAu ^ ks0 ^ ks1;
  const uint32_t ks[3] = {ks0, ks1, ks2};
  const uint32_t rot[2][4] = {{13u, 15u, 26u, 6u}, {17u, 29u, 16u, 24u}};
  x0 += ks0;
  x1 += ks1;
#pragma unroll
  for (int i = 0; i < 5; ++i) {
#pragma unroll
    for (int j = 0; j < 4; ++j) {
      const uint32_t r = rot[i & 1][j];
      x0 += x1;
      x1 = (x1 << r) | (x1 >> (32u - r));
      x1 ^= x0;
    }
    x0 += ks[(i + 1) % 3];
    x1 += ks[(i + 2) % 3] + (uint32_t)(i + 1);
  }
  o0 = x0;
  o1 = x1;
}

__device__ __forceinline__ float uniform_at(uint32_t j) {
  // partitionable threefry: ctr=(0,j), bits = o0^o1
  uint32_t o0, o1;
  threefry2x32(0u, j, o0, o1);
  const uint32_t bits = o0 ^ o1;
  uint32_t fb = (bits >> 9) | 0x3F800000u;
  float frac = __uint_as_float(fb) - 1.0f;
  return fmaxf(frac + 1e-10f, 1e-10f);
}

__device__ __forceinline__ double gumbel64_at(uint32_t j) {
  double t = -log((double)uniform_at(j));
  return -log(t);
}

__device__ __forceinline__ float gumbel32_at(uint32_t j) {
  float t = -logf(uniform_at(j));
  return -logf(t);
}

__device__ __forceinline__ double gelu_d(double x) {
  return 0.5 * x * (1.0 + erf(x * 0.70710678118654752440));
}

__device__ __forceinline__ float gelu_f(float x) {
  return 0.5f * x * (1.0f + erff(x * 0.70710678f));
}

// exact f64 MLP (identical op order to the round-2 kernel)
__device__ __noinline__ void mlp64(double acc, const float* __restrict__ W1,
                                   const float* __restrict__ b1,
                                   const float* __restrict__ W2,
                                   const float* __restrict__ b2,
                                   const float* __restrict__ W3,
                                   const float* __restrict__ b3, double& l0,
                                   double& l1) {
  double h1[16];
#pragma unroll
  for (int i = 0; i < 16; ++i)
    h1[i] = gelu_d(acc * (double)W1[i] + (double)b1[i]);
  double h2[8];
#pragma unroll
  for (int j = 0; j < 8; ++j) {
    double v = (double)b2[j];
#pragma unroll
    for (int i = 0; i < 16; ++i) v += h1[i] * (double)W2[i * 8 + j];
    h2[j] = gelu_d(v);
  }
  l0 = (double)b3[0];
  l1 = (double)b3[1];
#pragma unroll
  for (int j = 0; j < 8; ++j) {
    l0 += h2[j] * (double)W3[j * 2 + 0];
    l1 += h2[j] * (double)W3[j * 2 + 1];
  }
}

// ---------------------------------------------------------------------------
// Kernel 1: corr + MLP + gumbel -> binary adj, triangular tile grid.
// grid (136, 32): x = upper-tri (i<=j) 16x16-tile pair, y = b. 256 threads.
// ---------------------------------------------------------------------------
__global__ __launch_bounds__(256) void corr_adj_kernel(
    const float* __restrict__ fm,
    const float* __restrict__ W1, const float* __restrict__ b1,
    const float* __restrict__ W2, const float* __restrict__ b2,
    const float* __restrict__ W3, const float* __restrict__ b3,
    float* __restrict__ adj) {
  const int b = blockIdx.y;

  // decode upper-triangle pair (i <= j) from blockIdx.x in [0,136)
  int q = blockIdx.x, ti = 0;
  while (q >= 16 - ti) {
    q -= 16 - ti;
    ++ti;
  }
  const int tj = ti + q;
  const int s0 = ti * 16;
  const int t0 = tj * 16;
  const bool diag = (ti == tj);

  __shared__ double smS[16][258];
  __shared__ double smT[16][258];

  const int tid = threadIdx.x;
  {
    const float* baseS = fm + ((size_t)b * 256 + s0) * 256;
    const float* baseT = fm + ((size_t)b * 256 + t0) * 256;
#pragma unroll
    for (int p = 0; p < 4; ++p) {
      int idx = tid + p * 256;  // 0..1023 quads
      int r = idx >> 6;
      int c = (idx & 63) * 4;
      float4 v = *(const float4*)(baseS + r * 256 + c);
      smS[r][c + 0] = (double)v.x;
      smS[r][c + 1] = (double)v.y;
      smS[r][c + 2] = (double)v.z;
      smS[r][c + 3] = (double)v.w;
      if (!diag) {
        float4 w = *(const float4*)(baseT + r * 256 + c);
        smT[r][c + 0] = (double)w.x;
        smT[r][c + 1] = (double)w.y;
        smT[r][c + 2] = (double)w.z;
        smT[r][c + 3] = (double)w.w;
      }
    }
  }
  __syncthreads();

  const int sl = tid >> 4;
  const int tl = tid & 15;
  const double* Srow = smS[sl];
  const double* Trow = diag ? smS[tl] : smT[tl];

  // f64 dot, 4 independent accumulators for ILP
  double a0 = 0.0, a1 = 0.0, a2 = 0.0, a3 = 0.0;
  const double2* Sr = (const double2*)Srow;
  const double2* Tr = (const double2*)Trow;
#pragma unroll 8
  for (int k2 = 0; k2 < 128; k2 += 2) {
    double2 sa = Sr[k2];
    double2 sb = Sr[k2 + 1];
    double2 ta = Tr[k2];
    double2 tb = Tr[k2 + 1];
    a0 += sa.x * ta.x;
    a1 += sa.y * ta.y;
    a2 += sb.x * tb.x;
    a3 += sb.y * tb.y;
  }
  const double acc = (a0 + a2) + (a1 + a3);

  // f32 MLP
  const float cf = (float)acc;
  float h1[16];
#pragma unroll
  for (int i = 0; i < 16; ++i) h1[i] = gelu_f(fmaf(cf, W1[i], b1[i]));
  float h2[8];
#pragma unroll
  for (int j = 0; j < 8; ++j) {
    float v = b2[j];
#pragma unroll
    for (int i = 0; i < 16; ++i) v = fmaf(h1[i], W2[i * 8 + j], v);
    h2[j] = gelu_f(v);
  }
  float l0f = b3[0], l1f = b3[1];
#pragma unroll
  for (int j = 0; j < 8; ++j) {
    l0f = fmaf(h2[j], W3[j * 2 + 0], l0f);
    l1f = fmaf(h2[j], W3[j * 2 + 1], l1f);
  }
  const float dphi = l0f - l1f;

  const int s = s0 + sl;
  const int t = t0 + tl;

  bool haveExact = false;
  double l0e = 0.0, l1e = 0.0;

  // ---- decision for (s,t) ----
  {
    const uint32_t base =
        ((uint32_t)b << 16) | ((uint32_t)s << 8) | (uint32_t)t;
    float g0 = gumbel32_at(2u * base);
    float g1 = gumbel32_at(2u * base + 1u);
    float d = dphi - (g1 - g0);
    float a;
    if (fabsf(d) >= 1e-3f) {
      a = (d >= 0.0f) ? 1.0f : 0.0f;
    } else {
      if (!haveExact) {
        mlp64(acc, W1, b1, W2, b2, W3, b3, l0e, l1e);
        haveExact = true;
      }
      double G0 = gumbel64_at(2u * base);
      double G1 = gumbel64_at(2u * base + 1u);
      a = (l0e + G0 >= l1e + G1) ? 1.0f : 0.0f;
    }
    if (t == s) a = 1.0f;
    adj[((size_t)b << 16) | ((uint32_t)s << 8) | (uint32_t)t] = a;
  }

  // ---- mirror decision (t,s) for off-diagonal tile pairs ----
  if (!diag) {
    const uint32_t base =
        ((uint32_t)b << 16) | ((uint32_t)t << 8) | (uint32_t)s;
    float g0 = gumbel32_at(2u * base);
    float g1 = gumbel32_at(2u * base + 1u);
    float d = dphi - (g1 - g0);
    float a;
    if (fabsf(d) >= 1e-3f) {
      a = (d >= 0.0f) ? 1.0f : 0.0f;
    } else {
      if (!haveExact) {
        mlp64(acc, W1, b1, W2, b2, W3, b3, l0e, l1e);
        haveExact = true;
      }
      double G0 = gumbel64_at(2u * base);
      double G1 = gumbel64_at(2u * base + 1u);
      a = (l0e + G0 >= l1e + G1) ? 1.0f : 0.0f;
    }
    adj[((size_t)b << 16) | ((uint32_t)t << 8) | (uint32_t)s] = a;
  }
}

// ---------------------------------------------------------------------------
// Kernel 2: row-normalize adj in place. grid 8192 rows, 64 threads.
// ---------------------------------------------------------------------------
__global__ __launch_bounds__(64) void rownorm_kernel(float* __restrict__ adj) {
  const size_t row = blockIdx.x;
  float* p = adj + row * 256;
  const int lane = threadIdx.x;
  float4 v = ((const float4*)p)[lane];
  float sum = v.x + v.y + v.z + v.w;
#pragma unroll
  for (int off = 32; off; off >>= 1) sum += __shfl_xor(sum, off);
  const float r = 1.0f / sum;
  v.x *= r; v.y *= r; v.z *= r; v.w *= r;
  ((float4*)p)[lane] = v;
}

// ---------------------------------------------------------------------------
// Kernels 3/4: f32 GEMM, M=N=K=256 per batch z. BM=BN=128, BK=8, 256 thr.
// ---------------------------------------------------------------------------
__global__ __launch_bounds__(256) void gemm_kernel(
    const float* __restrict__ A, const float* __restrict__ B,
    const float* __restrict__ bias, float* __restrict__ C,
    int aDiv, int bShared) {
  const int z = blockIdx.z;
  const float* Ab = A + (size_t)(z / aDiv) * 65536;
  const float* Bb = bShared ? B : (B + (size_t)z * 65536);
  float* Cb = C + (size_t)z * 65536;

  const int row0 = blockIdx.y * 128;
  const int col0 = blockIdx.x * 128;

  __shared__ float As[8][132];
  __shared__ float Bs[8][132];

  const int tid = threadIdx.x;
  const int tx = tid & 15;
  const int ty = tid >> 4;

  float acc[2][2][4][4];
#pragma unroll
  for (int a = 0; a < 2; ++a)
#pragma unroll
    for (int bq = 0; bq < 2; ++bq)
#pragma unroll
      for (int i = 0; i < 4; ++i)
#pragma unroll
        for (int j = 0; j < 4; ++j) acc[a][bq][i][j] = 0.0f;

  for (int k0 = 0; k0 < 256; k0 += 8) {
    {
      int r = tid >> 1, c = (tid & 1) * 4;
      float4 v = *(const float4*)(Ab + (size_t)(row0 + r) * 256 + k0 + c);
      As[c + 0][r] = v.x;
      As[c + 1][r] = v.y;
      As[c + 2][r] = v.z;
      As[c + 3][r] = v.w;
    }
    {
      int r = tid >> 5, c = (tid & 31) * 4;
      *(float4*)(&Bs[r][c]) =
          *(const float4*)(Bb + (size_t)(k0 + r) * 256 + col0 + c);
    }
    __syncthreads();

#pragma unroll
    for (int kk = 0; kk < 8; ++kk) {
      float a0[4], a1[4], b0[4], b1[4];
      *(float4*)a0 = *(const float4*)(&As[kk][ty * 4]);
      *(float4*)a1 = *(const float4*)(&As[kk][ty * 4 + 64]);
      *(float4*)b0 = *(const float4*)(&Bs[kk][tx * 4]);
      *(float4*)b1 = *(const float4*)(&Bs[kk][tx * 4 + 64]);
#pragma unroll
      for (int i = 0; i < 4; ++i)
#pragma unroll
        for (int j = 0; j < 4; ++j) {
          acc[0][0][i][j] += a0[i] * b0[j];
          acc[0][1][i][j] += a0[i] * b1[j];
          acc[1][0][i][j] += a1[i] * b0[j];
          acc[1][1][i][j] += a1[i] * b1[j];
        }
    }
    __syncthreads();
  }

#pragma unroll
  for (int ih = 0; ih < 2; ++ih)
#pragma unroll
    for (int i = 0; i < 4; ++i) {
      const int row = row0 + ih * 64 + ty * 4 + i;
#pragma unroll
      for (int jh = 0; jh < 2; ++jh) {
        const int col = col0 + jh * 64 + tx * 4;
        float4 o;
        o.x = acc[ih][jh][i][0];
        o.y = acc[ih][jh][i][1];
        o.z = acc[ih][jh][i][2];
        o.w = acc[ih][jh][i][3];
        if (bias) {
          float4 bv = *(const float4*)(bias + col);
          o.x += bv.x; o.y += bv.y; o.z += bv.z; o.w += bv.w;
        }
        *(float4*)(Cb + (size_t)row * 256 + col) = o;
      }
    }
}

extern "C" void kernel_launch(void* const* d_in, const int* in_sizes, int n_in,
                              void* d_out, int out_size, void* d_ws,
                              size_t ws_size, hipStream_t stream) {
  const float* features = (const float*)d_in[0];
  const float* fm       = (const float*)d_in[1];
  const float* W1 = (const float*)d_in[2];
  const float* b1 = (const float*)d_in[3];
  const float* W2 = (const float*)d_in[4];
  const float* b2 = (const float*)d_in[5];
  const float* W3 = (const float*)d_in[6];
  const float* b3 = (const float*)d_in[7];
  const float* Wl = (const float*)d_in[8];
  const float* bl = (const float*)d_in[9];
  float* out = (float*)d_out;

  float* adj = (float*)d_ws;                          // 8.4 MB
  float* X = (float*)d_ws + (size_t)32 * 256 * 256;   // 33.5 MB

  corr_adj_kernel<<<dim3(136, 32), 256, 0, stream>>>(fm, W1, b1, W2, b2, W3,
                                                     b3, adj);
  rownorm_kernel<<<dim3(8192), 64, 0, stream>>>(adj);
  gemm_kernel<<<dim3(2, 2, 128), 256, 0, stream>>>(adj, features, nullptr, X,
                                                   4, 0);
  gemm_kernel<<<dim3(2, 2, 128), 256, 0, stream>>>(X, Wl, bl, out, 1, 1);
}